// Round 3
// baseline (648.936 us; speedup 1.0000x reference)
//
#include <hip/hip_runtime.h>

#define NN 12288
#define DD 128
#define NG 48

typedef float v4f __attribute__((ext_vector_type(4)));

// ---------------------------------------------------------------------------
// Kernel A: build graph boundary table start[0..NG] in workspace.
// start[g] = first index j with batch[j] >= g  (lower bound); start[NG] = NN.
// batch[] is sorted, so boundaries are where batch[j] != batch[j-1].
// One small block; ~12288 loads, trivially fast. Removes the 28-deep
// dependent binary-search chain from all 15360 main-kernel blocks.
// ---------------------------------------------------------------------------
__global__ __launch_bounds__(256) void build_starts(
    const int* __restrict__ batch, int* __restrict__ start)
{
    for (int j = threadIdx.x; j <= NN; j += 256) {
        if (j == NN) {
            const int b = batch[NN - 1];
            for (int g = b + 1; g <= NG; ++g) start[g] = NN;
        } else {
            const int b = batch[j];
            const int bprev = (j == 0) ? -1 : batch[j - 1];
            for (int g = bprev + 1; g <= b; ++g) start[g] = j;
        }
    }
}

// ---------------------------------------------------------------------------
// Kernel B: interleaved two-role grid (15360 blocks, 256 threads).
//   bid % 5 == 0  -> zero-slab block  (3072 total, 4 rows each):
//       streams float4 zeros over its rows, SKIPPING each row's band chunk
//       range [c0,c1]. Pure store stream, no dependent chains.
//   else          -> band block (12288 total, one row):
//       writes exactly chunks [c0,c1] as scalars: one column per thread,
//       one 512-FMA dot per matching column (parallel across lanes, not
//       serial per wave like R0-R2). Same fmaf order -> bit-exact.
// Coverage is disjoint (zero blocks skip exactly what band blocks write),
// so no intra-kernel ordering is needed. 1:5 interleave keeps the store
// pipe and the (tiny) compute load co-scheduled on every CU all the time.
// ---------------------------------------------------------------------------
__global__ __launch_bounds__(256) void segdec_main(
    const float* __restrict__ z1, const float* __restrict__ z2,
    const int* __restrict__ cls, const int* __restrict__ batch,
    const int* __restrict__ start, float* __restrict__ out)
{
    const int bid = (int)blockIdx.x;
    const int tid = (int)threadIdx.x;
    const v4f zero4 = {0.f, 0.f, 0.f, 0.f};

    if (bid % 5 == 0) {
        // ---------------- zero-slab block: rows [z*4, z*4+4) ----------------
        const int z = bid / 5;
        #pragma unroll
        for (int r = 0; r < 4; ++r) {
            const int i = (z << 2) + r;
            const int b = batch[i];
            const int lo = start[b];
            const int hi = start[b + 1];
            const int c0 = lo >> 2;
            const int c1 = (hi - 1) >> 2;
            v4f* __restrict__ orow = reinterpret_cast<v4f*>(out + (size_t)i * NN);
            #pragma unroll
            for (int k = 0; k < 12; ++k) {
                const int c = tid + (k << 8);
                if (c < c0 || c > c1) orow[c] = zero4;
            }
        }
    } else {
        // ---------------- band block: one row ------------------------------
        const int i = bid - bid / 5 - 1;          // bijective over [0, NN)
        const int cls_i = cls[i];
        const int b = batch[i];
        const int lo = start[b];
        const int hi = start[b + 1];
        const int c0 = lo >> 2;
        const int c1 = (hi - 1) >> 2;
        const int jbase = c0 << 2;
        const int ncols = ((c1 + 1) << 2) - jbase; // <= ~400 for this input

        const v4f* __restrict__ za = reinterpret_cast<const v4f*>(z1 + (size_t)i * DD);
        float* __restrict__ orow = out + (size_t)i * NN;

        for (int t = tid; t < ncols; t += 256) {
            const int j = jbase + t;
            float s = 0.f;
            if (cls_i < 24 && j >= lo && j < hi && j != i && cls[j] == cls_i) {
                const v4f* __restrict__ zb =
                    reinterpret_cast<const v4f*>(z2 + (size_t)j * DD);
                #pragma unroll
                for (int d = 0; d < DD / 4; ++d) {
                    const v4f a = za[d];
                    const v4f b4 = zb[d];
                    s = fmaf(a.x, b4.x, s);
                    s = fmaf(a.y, b4.y, s);
                    s = fmaf(a.z, b4.z, s);
                    s = fmaf(a.w, b4.w, s);
                }
            }
            orow[j] = s;
        }
    }
}

extern "C" void kernel_launch(void* const* d_in, const int* in_sizes, int n_in,
                              void* d_out, int out_size, void* d_ws, size_t ws_size,
                              hipStream_t stream) {
    const float* z1    = (const float*)d_in[0];
    const float* z2    = (const float*)d_in[1];
    const int*   cls   = (const int*)d_in[2];
    const int*   batch = (const int*)d_in[3];
    float*       out   = (float*)d_out;
    int*         start = (int*)d_ws;           // needs 49 ints

    build_starts<<<1, 256, 0, stream>>>(batch, start);
    segdec_main<<<NN + NN / 4, 256, 0, stream>>>(z1, z2, cls, batch, start, out);
}